// Round 3
// baseline (13716.437 us; speedup 1.0000x reference)
//
#include <hip/hip_runtime.h>
#include <math.h>

#define NCH   128          // chains = 2*B (0..63 = generated, 64..127 = true)
#define SLEN  256
#define HDIM  1024
#define N3    3072

typedef __attribute__((ext_vector_type(8))) __bf16 bf16x8;
typedef __attribute__((ext_vector_type(4))) float  f32x4;

__device__ __forceinline__ f32x4 mfma_bf16(bf16x8 a, bf16x8 b, f32x4 c) {
  return __builtin_amdgcn_mfma_f32_16x16x32_bf16(a, b, c, 0, 0, 0);
}

// ---- agent-scope (sc1 / IC-coherent) accessors
__device__ __forceinline__ float ld_sc1_f32(const float* p) {
  return __hip_atomic_load(p, __ATOMIC_RELAXED, __HIP_MEMORY_SCOPE_AGENT);
}
__device__ __forceinline__ void st_sc1_f32(float* p, float v) {
  __hip_atomic_store(p, v, __ATOMIC_RELAXED, __HIP_MEMORY_SCOPE_AGENT);
}
__device__ __forceinline__ unsigned long long ld_sc1_u64(const unsigned long long* p) {
  return __hip_atomic_load(p, __ATOMIC_RELAXED, __HIP_MEMORY_SCOPE_AGENT);
}
__device__ __forceinline__ void st_sc1_u32(unsigned int* p, unsigned int v) {
  __hip_atomic_store(p, v, __ATOMIC_RELAXED, __HIP_MEMORY_SCOPE_AGENT);
}
__device__ __forceinline__ int ld_sc1_i32(const int* p) {
  return __hip_atomic_load(p, __ATOMIC_RELAXED, __HIP_MEMORY_SCOPE_AGENT);
}
__device__ __forceinline__ void st_sc1_i32(int* p, int v) {
  __hip_atomic_store(p, v, __ATOMIC_RELAXED, __HIP_MEMORY_SCOPE_AGENT);
}

// ---------------------------------------------------------------------------
// prep: weight hi/lo splits + x packing (bf16 hi/lo in one u32) + zero
// h0s slot 0 / H1pk / flags — one flat-indexed dispatch.
// ---------------------------------------------------------------------------
__global__ __launch_bounds__(256) void prep(
    const float* __restrict__ Whh0, const float* __restrict__ Whh1,
    const float* __restrict__ Wih1, const float* __restrict__ Wih0,
    const float* __restrict__ gen,  const float* __restrict__ tru,
    __bf16* __restrict__ Whh0h, __bf16* __restrict__ Whh0l,
    __bf16* __restrict__ Whh1h, __bf16* __restrict__ Whh1l,
    __bf16* __restrict__ Wih1h, __bf16* __restrict__ Wih1l,
    __bf16* __restrict__ Wih0h, __bf16* __restrict__ Wih0l,
    unsigned int* __restrict__ xpk,    // [NCH][SLEN][512] packed u32
    unsigned int* __restrict__ h0s,    // [NCH][SLEN+1][HDIM]; slot 0 zeroed
    unsigned int* __restrict__ H1pk,   // [NCH][HDIM] zeroed
    int* __restrict__ flags)           // 512 ints zeroed
{
  const int NB = N3 * HDIM;      // 3,145,728
  const int NS = N3 * 512;       // 1,572,864
  const int NX = NCH * SLEN * 512;
  int i = blockIdx.x * 256 + threadIdx.x;
  if (i < 3 * NB + NS) {
    const float* src; __bf16 *dh, *dl; int j;
    if (i < NB)            { src = Whh0; dh = Whh0h; dl = Whh0l; j = i; }
    else if (i < 2 * NB)   { src = Whh1; dh = Whh1h; dl = Whh1l; j = i - NB; }
    else if (i < 3 * NB)   { src = Wih1; dh = Wih1h; dl = Wih1l; j = i - 2 * NB; }
    else                   { src = Wih0; dh = Wih0h; dl = Wih0l; j = i - 3 * NB; }
    float x = src[j];
    __bf16 h = (__bf16)x;
    dh[j] = h;
    dl[j] = (__bf16)(x - (float)h);
    return;
  }
  i -= 3 * NB + NS;
  if (i < NX) {
    float x = (i < NX / 2) ? gen[i] : tru[i - NX / 2];
    __bf16 h = (__bf16)x;
    __bf16 l = (__bf16)(x - (float)h);
    unsigned short hs, ls;
    __builtin_memcpy(&hs, &h, 2);
    __builtin_memcpy(&ls, &l, 2);
    xpk[i] = (unsigned int)hs | ((unsigned int)ls << 16);
    return;
  }
  i -= NX;
  if (i < NCH * HDIM) {              // h0s slot 0 (h0(-1) = 0)
    int ch = i >> 10, k = i & 1023;
    h0s[(size_t)ch * (SLEN + 1) * HDIM + k] = 0u;
    return;
  }
  i -= NCH * HDIM;
  if (i < NCH * HDIM) { H1pk[i] = 0u; return; }
  i -= NCH * HDIM;
  if (i < 512) flags[i] = 0;
}

// ---------------------------------------------------------------------------
// Cooperative W-tile load for the burst projection: 96 rows x 64 cols (hi+lo)
// into LDS [buf][part][6t][16r][72(pad)] bf16.  1536 b128 pieces, 3/thread.
// ---------------------------------------------------------------------------
__device__ __forceinline__ void load_wtile(
    __bf16* wt, const __bf16* __restrict__ Wph, const __bf16* __restrict__ Wpl,
    int KIN, int ct, int chunk, int buf, int tid)
{
#pragma unroll
  for (int it = 0; it < 3; ++it) {
    const int idx = tid + it * 512;               // 0..1535
    const int part = (idx >= 768) ? 1 : 0;
    const int rem  = idx - part * 768;
    const int row96 = rem >> 3;                   // 0..95
    const int c8    = rem & 7;
    const int gate  = row96 >> 5;
    const int r32   = row96 & 31;
    const int t     = gate * 2 + (r32 >> 4);
    const int r16   = r32 & 15;
    const size_t grow = (size_t)(gate * 1024 + ct * 32 + r32);
    const __bf16* src = (part ? Wpl : Wph) + grow * KIN + chunk * 64 + c8 * 8;
    __bf16* dst = wt + (size_t)(((buf * 2 + part) * 6 + t) * 16 + r16) * 72 + c8 * 8;
    *(bf16x8*)dst = *(const bf16x8*)src;
  }
}

// ---------------------------------------------------------------------------
// recur_fused: persistent recurrence with FUSED input projection + both LNs.
// 256 blocks x 512 thr (1 block/CU). Group gid = bid>>5 owns chains
// [gid*16,+16); block ct = bid&31 owns cols [ct*32,+32) of each gate.
//
// Every 8 steps a "burst" computes the input projection pi for the next 8
// timesteps: the block's 96xKIN weight slice streams through LDS once
// (8x amortized), waves are split (gate g, u-half) so each B-fragment is
// reused 4x from LDS; each (t,u) output is one full-K kc-ascending
// (hh,hl,lh) accumulation chain — bit-identical to the old xproj kernel.
// piv results are parked in a 48KB LDS cache and consumed per step.
//
// The per-step recurrent GEMM + LN-stats exchange + phase B are the proven
// round-0 structure (red pad 20, epoch-based flags: value = base+dt+1).
// Layer 0 publishes packed bf16 hi/lo h-history h0s[ch][t+1][:] (sc1);
// layer 1 (separate launch, after L0 completed) reads h0s with plain cached
// loads in its burst — no cross-layer flags needed.
// ---------------------------------------------------------------------------
__global__ __launch_bounds__(512, 2) void recur_fused(
    const __bf16* __restrict__ Wrh, const __bf16* __restrict__ Wrl,  // recurrent
    const __bf16* __restrict__ Wph, const __bf16* __restrict__ Wpl,  // input proj
    const int KIN, const int nchunk,                                  // 512/8 or 1024/16
    const float* __restrict__ bih, const float* __restrict__ bhh,
    const float* __restrict__ giw, const float* __restrict__ gib,
    const float* __restrict__ ghw, const float* __restrict__ ghb,
    const unsigned int* __restrict__ Ain, const size_t inCh, const int inT,
    const unsigned int* __restrict__ Arec, const size_t recCh, const int recT,
    unsigned int* __restrict__ Pub, const size_t pubCh, const int pubT,
    float* __restrict__ hfin,                 // layer1: h_cur1; layer0: null
    float* __restrict__ stats_part,           // [8][32][192]
    int* __restrict__ fAg, int* __restrict__ fBg,   // [8*32] each
    const int base)
{
  __shared__ float red[15360];     // 61,440B: k-reduce (pad 20) / W-tiles / gather
  __shared__ float pivb[12288];    // 49,152B: piv cache [u8][m16][g3][col32]
  __shared__ float sred[1536];     // [w][m][12]
  __shared__ float sstat[192];     // [m][12]

  const int tid  = threadIdx.x;
  const int bid  = blockIdx.x;
  const int gid  = bid >> 5;
  const int ct   = bid & 31;
  const int lane = tid & 63;
  const int w    = tid >> 6;        // wave 0..7 -> k-slice (rec GEMM)
  const int q    = lane >> 4;
  const int c15  = lane & 15;
  const int m    = tid & 15;        // phase-B chain within group
  const int col  = tid >> 4;        // 0..31 within col slice
  const int ch   = gid * 16 + m;
  const int Hcol = ct * 32 + col;
  const int chA  = gid * 16 + c15;  // phase-A chain (A-row)

  // ---- recurrent weight fragments in registers (hi/lo) ----
  bf16x8 rh[6][4], rl[6][4];
  const int kwr = w * 128;
#pragma unroll
  for (int t = 0; t < 6; ++t) {
    const int gate = t >> 1, half = t & 1;
    const size_t nrow = (size_t)(gate * 1024 + ct * 32 + half * 16 + c15);
#pragma unroll
    for (int kc = 0; kc < 4; ++kc) {
      const size_t off = nrow * HDIM + kwr + kc * 32 + q * 8;
      rh[t][kc] = *(const bf16x8*)(Wrh + off);
      rl[t][kc] = *(const bf16x8*)(Wrl + off);
    }
  }

  // per-thread constants (phase B)
  const float bI0 = bih[Hcol], bI1 = bih[1024 + Hcol], bI2 = bih[2048 + Hcol];
  const float bH0 = bhh[Hcol], bH1 = bhh[1024 + Hcol], bH2 = bhh[2048 + Hcol];
  const float iw0 = giw[Hcol], iw1 = giw[1024 + Hcol], iw2 = giw[2048 + Hcol];
  const float ib0 = gib[Hcol], ib1 = gib[1024 + Hcol], ib2 = gib[2048 + Hcol];
  const float lw0 = ghw[Hcol], lw1 = ghw[1024 + Hcol], lw2 = ghw[2048 + Hcol];
  const float lb0 = ghb[Hcol], lb1 = ghb[1024 + Hcol], lb2 = ghb[2048 + Hcol];
  float hprev = 0.f;

  const unsigned int* ainb  = Ain + (size_t)chA * inCh;                // + q*8 at use
  const unsigned int* arecb = Arec + (size_t)chA * recCh + kwr + q * 8;
  unsigned int* pubp = Pub + (size_t)ch * pubCh + Hcol;
  float* my_part = stats_part + ((size_t)gid * 32 + ct) * 192;
  int* fA = fAg + (gid << 5);
  int* fB = fBg + (gid << 5);
  const int pidx = lane & 31;
  const int g2 = w >> 1, uh = w & 1;   // burst roles (waves 0..5 compute)

  for (int dt = 0; dt < SLEN; ++dt) {
    // =====================================================================
    // burst: input projection for steps dt..dt+7 -> pivb
    // =====================================================================
    if ((dt & 7) == 0) {
      __bf16* wt = (__bf16*)red;
      f32x4 pacc[2][4];
#pragma unroll
      for (int a = 0; a < 2; ++a)
#pragma unroll
        for (int b = 0; b < 4; ++b) pacc[a][b] = (f32x4){0.f, 0.f, 0.f, 0.f};

      load_wtile(wt, Wph, Wpl, KIN, ct, 0, 0, tid);
      __syncthreads();
      for (int c = 0; c < nchunk; ++c) {
        if (c + 1 < nchunk) load_wtile(wt, Wph, Wpl, KIN, ct, c + 1, (c + 1) & 1, tid);
        if (w < 6) {
          const __bf16* bhi = wt + (size_t)((c & 1) * 2 + 0) * 6912;
          const __bf16* blo = wt + (size_t)((c & 1) * 2 + 1) * 6912;
#pragma unroll
          for (int uu = 0; uu < 4; ++uu) {
            const unsigned int* ap = ainb + (size_t)(dt + uh * 4 + uu) * inT + c * 64 + q * 8;
            unsigned long long a8[8];
#pragma unroll
            for (int ks = 0; ks < 2; ++ks)
#pragma unroll
              for (int j = 0; j < 4; ++j)
                a8[ks * 4 + j] = ((const unsigned long long*)(ap + ks * 32))[j];
#pragma unroll
            for (int ks = 0; ks < 2; ++ks) {
              unsigned int ua[8];
#pragma unroll
              for (int j = 0; j < 4; ++j) {
                ua[2 * j]     = (unsigned int)a8[ks * 4 + j];
                ua[2 * j + 1] = (unsigned int)(a8[ks * 4 + j] >> 32);
              }
              union { unsigned int d[4]; bf16x8 v; } uah, ual;
#pragma unroll
              for (int d = 0; d < 4; ++d) {
                uah.d[d] = __builtin_amdgcn_perm(ua[2 * d + 1], ua[2 * d], 0x05040100u);
                ual.d[d] = __builtin_amdgcn_perm(ua[2 * d + 1], ua[2 * d], 0x07060302u);
              }
#pragma unroll
              for (int tt = 0; tt < 2; ++tt) {
                const int t = g2 * 2 + tt;
                const size_t bo = (size_t)(t * 16 + c15) * 72 + ks * 32 + q * 8;
                bf16x8 wbh = *(const bf16x8*)(bhi + bo);
                bf16x8 wbl = *(const bf16x8*)(blo + bo);
                pacc[tt][uu] = mfma_bf16(uah.v, wbh, pacc[tt][uu]);
                pacc[tt][uu] = mfma_bf16(uah.v, wbl, pacc[tt][uu]);
                pacc[tt][uu] = mfma_bf16(ual.v, wbh, pacc[tt][uu]);
              }
            }
          }
        }
        __syncthreads();
      }
      if (w < 6) {
#pragma unroll
        for (int uu = 0; uu < 4; ++uu)
#pragma unroll
          for (int tt = 0; tt < 2; ++tt)
#pragma unroll
            for (int rr = 0; rr < 4; ++rr)
              pivb[(((uh * 4 + uu) * 16 + (q * 4 + rr)) * 3 + g2) * 32 + tt * 16 + c15] =
                  pacc[tt][uu][rr];
      }
      __syncthreads();
    }

    // =====================================================================
    // per-step recurrence (round-0 proven structure)
    // =====================================================================
    // ---- wait until h(dt-1) published by all 32 blocks of the group ----
    if (w == 0 && dt > 0) {
      while (true) {
        int v = ld_sc1_i32(fB + pidx);
        if (!__any(v < base + dt)) break;
        __builtin_amdgcn_s_sleep(1);
      }
    }
    __syncthreads();
    __asm__ __volatile__("" ::: "memory");

    // ---- rec GEMM slice (k-split across waves) ----
    f32x4 acc[6];
#pragma unroll
    for (int t = 0; t < 6; ++t) acc[t] = (f32x4){0.f, 0.f, 0.f, 0.f};

    const unsigned int* arow = arecb + (size_t)dt * recT;
    unsigned long long abuf[2][4];
#pragma unroll
    for (int j = 0; j < 4; ++j) {
      abuf[0][j] = ld_sc1_u64((const unsigned long long*)(arow + 0 * 32) + j);
      abuf[1][j] = ld_sc1_u64((const unsigned long long*)(arow + 1 * 32) + j);
    }
#pragma unroll
    for (int kc = 0; kc < 4; ++kc) {
      unsigned int u[8];
#pragma unroll
      for (int j = 0; j < 4; ++j) {
        u[2 * j]     = (unsigned int)(abuf[kc & 1][j]);
        u[2 * j + 1] = (unsigned int)(abuf[kc & 1][j] >> 32);
      }
      union { unsigned int d[4]; bf16x8 v; } uah, ual;
#pragma unroll
      for (int d = 0; d < 4; ++d) {
        uah.d[d] = __builtin_amdgcn_perm(u[2 * d + 1], u[2 * d], 0x05040100u);
        ual.d[d] = __builtin_amdgcn_perm(u[2 * d + 1], u[2 * d], 0x07060302u);
      }
      if (kc < 2) {
#pragma unroll
        for (int j = 0; j < 4; ++j)
          abuf[kc & 1][j] = ld_sc1_u64(
              (const unsigned long long*)(arow + (kc + 2) * 32) + j);
      }
      bf16x8 ah = uah.v, al = ual.v;
#pragma unroll
      for (int t = 0; t < 6; ++t) {
        acc[t] = mfma_bf16(ah, rh[t][kc], acc[t]);
        acc[t] = mfma_bf16(ah, rl[t][kc], acc[t]);
        acc[t] = mfma_bf16(al, rh[t][kc], acc[t]);
      }
    }

    // ---- k-reduce via LDS (pad 20, bank-safe) ----
#pragma unroll
    for (int t = 0; t < 6; ++t) {
      const int idx = ((w * 6 + t) * 16 + c15) * 20 + q * 4;
      *(f32x4*)&red[idx] = acc[t];
    }
    __syncthreads();

    float phv0 = 0.f, phv1 = 0.f, phv2 = 0.f;
    {
      const int cn = col & 15;
      const int hi = col >> 4;
#pragma unroll
      for (int w8 = 0; w8 < 8; ++w8) {
        phv0 += red[((w8 * 6 + 0 + hi) * 16 + cn) * 20 + m];
        phv1 += red[((w8 * 6 + 2 + hi) * 16 + cn) * 20 + m];
        phv2 += red[((w8 * 6 + 4 + hi) * 16 + cn) * 20 + m];
      }
    }
    phv0 += bH0; phv1 += bH1; phv2 += bH2;

    const int u7 = dt & 7;
    const float piv0 = pivb[((u7 * 16 + m) * 3 + 0) * 32 + col] + bI0;
    const float piv1 = pivb[((u7 * 16 + m) * 3 + 1) * 32 + col] + bI1;
    const float piv2 = pivb[((u7 * 16 + m) * 3 + 2) * 32 + col] + bI2;

    // ---- per-wave LN partials (ph AND pi) -> sred ----
    {
      float s0 = phv0, s1 = phv1, s2 = phv2;
      float q0 = phv0 * phv0, q1 = phv1 * phv1, q2 = phv2 * phv2;
      float s3 = piv0, s4 = piv1, s5 = piv2;
      float q3 = piv0 * piv0, q4 = piv1 * piv1, q5 = piv2 * piv2;
#pragma unroll
      for (int mm = 16; mm <= 32; mm <<= 1) {
        s0 += __shfl_xor(s0, mm); q0 += __shfl_xor(q0, mm);
        s1 += __shfl_xor(s1, mm); q1 += __shfl_xor(q1, mm);
        s2 += __shfl_xor(s2, mm); q2 += __shfl_xor(q2, mm);
        s3 += __shfl_xor(s3, mm); q3 += __shfl_xor(q3, mm);
        s4 += __shfl_xor(s4, mm); q4 += __shfl_xor(q4, mm);
        s5 += __shfl_xor(s5, mm); q5 += __shfl_xor(q5, mm);
      }
      if (lane < 16) {
        const int b = (w * 16 + lane) * 12;
        sred[b + 0] = s0;  sred[b + 1] = q0;
        sred[b + 2] = s1;  sred[b + 3] = q1;
        sred[b + 4] = s2;  sred[b + 5] = q2;
        sred[b + 6] = s3;  sred[b + 7] = q3;
        sred[b + 8] = s4;  sred[b + 9] = q4;
        sred[b + 10] = s5; sred[b + 11] = q5;
      }
    }
    __syncthreads();

    // ---- block partials -> IC ----
    if (tid < 192) {
      const int m12 = tid / 12;
      const int r12 = tid - m12 * 12;
      float v = 0.f;
#pragma unroll
      for (int w8 = 0; w8 < 8; ++w8) v += sred[(w8 * 16 + m12) * 12 + r12];
      st_sc1_f32(&my_part[tid], v);
    }
    __syncthreads();   // drains vmcnt on all waves -> partials visible at IC
    if (tid == 0) st_sc1_i32((int*)fA + ct, base + dt + 1);

    // ---- wait all blocks' partials ----
    if (w == 0) {
      while (true) {
        int v = ld_sc1_i32(fA + pidx);
        if (!__any(v < base + dt + 1)) break;
        __builtin_amdgcn_s_sleep(1);
      }
    }
    __syncthreads();
    __asm__ __volatile__("" ::: "memory");

    // ---- gather stats: 512 threads, 12 loads each; 2-stage reduce ----
    {
      const int cidx = tid >> 4;   // source block 0..31
      const float* sp = stats_part + ((size_t)gid * 32 + cidx) * 192 + m * 12;
      float p0 = ld_sc1_f32(sp + 0),  p1 = ld_sc1_f32(sp + 1),  p2 = ld_sc1_f32(sp + 2);
      float p3 = ld_sc1_f32(sp + 3),  p4 = ld_sc1_f32(sp + 4),  p5 = ld_sc1_f32(sp + 5);
      float p6 = ld_sc1_f32(sp + 6),  p7 = ld_sc1_f32(sp + 7),  p8 = ld_sc1_f32(sp + 8);
      float p9 = ld_sc1_f32(sp + 9),  p10 = ld_sc1_f32(sp + 10), p11 = ld_sc1_f32(sp + 11);
      p0 += __shfl_xor(p0, 16); p1 += __shfl_xor(p1, 16); p2 += __shfl_xor(p2, 16);
      p3 += __shfl_xor(p3, 16); p4 += __shfl_xor(p4, 16); p5 += __shfl_xor(p5, 16);
      p6 += __shfl_xor(p6, 16); p7 += __shfl_xor(p7, 16); p8 += __shfl_xor(p8, 16);
      p9 += __shfl_xor(p9, 16); p10 += __shfl_xor(p10, 16); p11 += __shfl_xor(p11, 16);
      p0 += __shfl_xor(p0, 32); p1 += __shfl_xor(p1, 32); p2 += __shfl_xor(p2, 32);
      p3 += __shfl_xor(p3, 32); p4 += __shfl_xor(p4, 32); p5 += __shfl_xor(p5, 32);
      p6 += __shfl_xor(p6, 32); p7 += __shfl_xor(p7, 32); p8 += __shfl_xor(p8, 32);
      p9 += __shfl_xor(p9, 32); p10 += __shfl_xor(p10, 32); p11 += __shfl_xor(p11, 32);
      if (lane < 16) {           // per-wave partial over its 4 source blocks
        const int b = w * 200 + lane * 12;    // reuse `red`, stride 200
        red[b + 0] = p0;  red[b + 1] = p1;  red[b + 2] = p2;
        red[b + 3] = p3;  red[b + 4] = p4;  red[b + 5] = p5;
        red[b + 6] = p6;  red[b + 7] = p7;  red[b + 8] = p8;
        red[b + 9] = p9;  red[b + 10] = p10; red[b + 11] = p11;
      }
    }
    __syncthreads();
    if (tid < 192) {
      float v = 0.f;
#pragma unroll
      for (int w8 = 0; w8 < 8; ++w8) v += red[w8 * 200 + tid];
      sstat[tid] = v;
    }
    __syncthreads();

    // ---- phase B: both LNs + gate math + publish h(dt) ----
    {
      const int b = m * 12;
      const float mh0 = sstat[b + 0] * (1.f / 1024.f);
      const float vh0 = sstat[b + 1] * (1.f / 1024.f) - mh0 * mh0;
      const float mh1 = sstat[b + 2] * (1.f / 1024.f);
      const float vh1 = sstat[b + 3] * (1.f / 1024.f) - mh1 * mh1;
      const float mh2 = sstat[b + 4] * (1.f / 1024.f);
      const float vh2 = sstat[b + 5] * (1.f / 1024.f) - mh2 * mh2;
      const float mi0 = sstat[b + 6] * (1.f / 1024.f);
      const float vi0 = sstat[b + 7] * (1.f / 1024.f) - mi0 * mi0;
      const float mi1 = sstat[b + 8] * (1.f / 1024.f);
      const float vi1 = sstat[b + 9] * (1.f / 1024.f) - mi1 * mi1;
      const float mi2 = sstat[b + 10] * (1.f / 1024.f);
      const float vi2 = sstat[b + 11] * (1.f / 1024.f) - mi2 * mi2;
      const float nh0 = (phv0 - mh0) * rsqrtf(vh0 + 1e-5f) * lw0 + lb0;
      const float nh1 = (phv1 - mh1) * rsqrtf(vh1 + 1e-5f) * lw1 + lb1;
      const float nh2 = (phv2 - mh2) * rsqrtf(vh2 + 1e-5f) * lw2 + lb2;
      const float ni0 = (piv0 - mi0) * rsqrtf(vi0 + 1e-5f) * iw0 + ib0;
      const float ni1 = (piv1 - mi1) * rsqrtf(vi1 + 1e-5f) * iw1 + ib1;
      const float ni2 = (piv2 - mi2) * rsqrtf(vi2 + 1e-5f) * iw2 + ib2;
      const float r  = 1.f / (1.f + expf(-(ni0 + nh0)));
      const float z  = 1.f / (1.f + expf(-(ni1 + nh1)));
      const float nn = tanhf(ni2 + r * nh2);
      const float hn = (1.f - z) * nn + z * hprev;
      hprev = hn;
      const __bf16 hb = (__bf16)hn;
      const __bf16 lo = (__bf16)(hn - (float)hb);
      unsigned short hs, ls;
      __builtin_memcpy(&hs, &hb, 2);
      __builtin_memcpy(&ls, &lo, 2);
      st_sc1_u32(pubp + (size_t)dt * pubT,
                 (unsigned int)hs | ((unsigned int)ls << 16));
      if (hfin && dt == SLEN - 1) hfin[(size_t)ch * HDIM + Hcol] = hn;
    }
    __syncthreads();   // drains vmcnt -> h visible at IC
    if (tid == 0) st_sc1_i32((int*)fB + ct, base + dt + 1);
  }
}

// ---------------------------------------------------------------------------
// readout: label (128 x dot-1024) + loss reduce, one dispatch.
// ---------------------------------------------------------------------------
__global__ __launch_bounds__(1024) void readout(const float* __restrict__ h,
    const float* __restrict__ Wout, const float* __restrict__ bout,
    float* __restrict__ out)
{
  const int tid  = threadIdx.x;
  const int lane = tid & 63;
  const int w    = tid >> 6;
  __shared__ float lab[128];
  __shared__ float rg[2], rt[2];
  const int c  = w * 8 + (lane >> 3);
  const int j0 = (lane & 7) * 128;
  const float* hp = h + (size_t)c * HDIM + j0;
  float s = 0.f;
#pragma unroll
  for (int j = 0; j < 128; j += 4) {
    float4 v  = *(const float4*)(hp + j);
    float4 wv = *(const float4*)(Wout + j0 + j);
    s += v.x * wv.x + v.y * wv.y + v.z * wv.z + v.w * wv.w;
  }
  s += __shfl_xor(s, 1);
  s += __shfl_xor(s, 2);
  s += __shfl_xor(s, 4);
  if ((lane & 7) == 0) lab[c] = s + bout[0];
  __syncthreads();
  if (tid < 128) {
    float v = lab[tid];
    float g = (tid < 64) ? v : 0.f;
    float t = (tid >= 64) ? v : 0.f;
#pragma unroll
    for (int off = 32; off > 0; off >>= 1) {
      g += __shfl_down(g, off);
      t += __shfl_down(t, off);
    }
    if ((tid & 63) == 0) { rg[tid >> 6] = g; rt[tid >> 6] = t; }
  }
  __syncthreads();
  if (tid == 0) {
    float gm = (rg[0] + rg[1]) * (1.f / 64.f);
    float tm = (rt[0] + rt[1]) * (1.f / 64.f);
    out[0] = -tm + gm;
    out[1] = -gm;
  }
}

// ---------------------------------------------------------------------------
extern "C" void kernel_launch(void* const* d_in, const int* in_sizes, int n_in,
                              void* d_out, int out_size, void* d_ws, size_t ws_size,
                              hipStream_t stream)
{
  const float* gen  = (const float*)d_in[0];
  const float* tru  = (const float*)d_in[1];
  const float* Wih0 = (const float*)d_in[2];
  const float* Whh0 = (const float*)d_in[3];
  const float* bih0 = (const float*)d_in[4];
  const float* bhh0 = (const float*)d_in[5];
  const float* gig0 = (const float*)d_in[6];
  const float* gib0 = (const float*)d_in[7];
  const float* ghg0 = (const float*)d_in[8];
  const float* ghb0 = (const float*)d_in[9];
  const float* Wih1 = (const float*)d_in[10];
  const float* Whh1 = (const float*)d_in[11];
  const float* bih1 = (const float*)d_in[12];
  const float* bhh1 = (const float*)d_in[13];
  const float* gig1 = (const float*)d_in[14];
  const float* gib1 = (const float*)d_in[15];
  const float* ghg1 = (const float*)d_in[16];
  const float* ghb1 = (const float*)d_in[17];
  const float* Wout = (const float*)d_in[18];
  const float* bout = (const float*)d_in[19];
  float* out = (float*)d_out;

  // ---- bf16 hi/lo weights ----
  __bf16* bp = (__bf16*)d_ws;
  __bf16* Whh0h = bp;  bp += (size_t)N3 * HDIM;
  __bf16* Whh0l = bp;  bp += (size_t)N3 * HDIM;
  __bf16* Whh1h = bp;  bp += (size_t)N3 * HDIM;
  __bf16* Whh1l = bp;  bp += (size_t)N3 * HDIM;
  __bf16* Wih1h = bp;  bp += (size_t)N3 * HDIM;
  __bf16* Wih1l = bp;  bp += (size_t)N3 * HDIM;
  __bf16* Wih0h = bp;  bp += (size_t)N3 * 512;
  __bf16* Wih0l = bp;  bp += (size_t)N3 * 512;

  // ---- u32 region ----
  unsigned int* h0s  = (unsigned int*)bp;                       // [NCH][SLEN+1][HDIM]
  unsigned int* H1pk = h0s + (size_t)NCH * (SLEN + 1) * HDIM;   // [NCH][HDIM]
  unsigned int* xpk  = H1pk + (size_t)NCH * HDIM;               // [NCH][SLEN][512]

  // ---- f32 region ----
  float* fp     = (float*)(xpk + (size_t)NCH * SLEN * 512);
  float* h_cur1 = fp;   fp += (size_t)NCH * HDIM;
  float* stats  = fp;   fp += 8 * 32 * 192;
  int*   flag_a = (int*)fp;          // 256 ints
  int*   flag_b = flag_a + 256;      // 256 ints

  // ---- prep ----
  {
    const int total = 3 * (N3 * HDIM) + (N3 * 512) + NCH * SLEN * 512
                      + 2 * NCH * HDIM + 512;
    prep<<<(total + 255) / 256, 256, 0, stream>>>(
        Whh0, Whh1, Wih1, Wih0, gen, tru,
        Whh0h, Whh0l, Whh1h, Whh1l, Wih1h, Wih1l, Wih0h, Wih0l,
        xpk, h0s, H1pk, flag_a);
  }

  // ---- layer 0: fused proj-burst + recurrence; publishes h0 history ----
  recur_fused<<<256, 512, 0, stream>>>(
      Whh0h, Whh0l, Wih0h, Wih0l, 512, 8,
      bih0, bhh0, gig0, gib0, ghg0, ghb0,
      xpk, (size_t)(SLEN * 512), 512,
      h0s, (size_t)((SLEN + 1) * HDIM), HDIM,
      h0s + HDIM, (size_t)((SLEN + 1) * HDIM), HDIM,
      (float*)nullptr, stats, flag_a, flag_b, 0);

  // ---- layer 1: input = h0 history (plain cached reads in burst) ----
  recur_fused<<<256, 512, 0, stream>>>(
      Whh1h, Whh1l, Wih1h, Wih1l, 1024, 16,
      bih1, bhh1, gig1, gib1, ghg1, ghb1,
      h0s + HDIM, (size_t)((SLEN + 1) * HDIM), HDIM,
      H1pk, (size_t)HDIM, 0,
      H1pk, (size_t)HDIM, 0,
      h_cur1, stats, flag_a, flag_b, SLEN);

  // ---- readout ----
  readout<<<1, 1024, 0, stream>>>(h_cur1, Wout, bout, out);
}

// Round 6
// 11304.648 us; speedup vs baseline: 1.2133x; 1.2133x over previous
//
#include <hip/hip_runtime.h>
#include <math.h>

#define NCH   128          // chains = 2*B (0..63 = generated, 64..127 = true)
#define SLEN  256
#define HDIM  1024
#define N3    3072

typedef __attribute__((ext_vector_type(8))) __bf16 bf16x8;
typedef __attribute__((ext_vector_type(4))) float  f32x4;

__device__ __forceinline__ f32x4 mfma_bf16(bf16x8 a, bf16x8 b, f32x4 c) {
  return __builtin_amdgcn_mfma_f32_16x16x32_bf16(a, b, c, 0, 0, 0);
}

// ---- agent-scope (sc1 / IC-coherent) accessors
__device__ __forceinline__ float ld_sc1_f32(const float* p) {
  return __hip_atomic_load(p, __ATOMIC_RELAXED, __HIP_MEMORY_SCOPE_AGENT);
}
__device__ __forceinline__ void st_sc1_f32(float* p, float v) {
  __hip_atomic_store(p, v, __ATOMIC_RELAXED, __HIP_MEMORY_SCOPE_AGENT);
}
__device__ __forceinline__ unsigned long long ld_sc1_u64(const unsigned long long* p) {
  return __hip_atomic_load(p, __ATOMIC_RELAXED, __HIP_MEMORY_SCOPE_AGENT);
}
__device__ __forceinline__ void st_sc1_u32(unsigned int* p, unsigned int v) {
  __hip_atomic_store(p, v, __ATOMIC_RELAXED, __HIP_MEMORY_SCOPE_AGENT);
}
__device__ __forceinline__ int ld_sc1_i32(const int* p) {
  return __hip_atomic_load(p, __ATOMIC_RELAXED, __HIP_MEMORY_SCOPE_AGENT);
}
__device__ __forceinline__ void st_sc1_i32(int* p, int v) {
  __hip_atomic_store(p, v, __ATOMIC_RELAXED, __HIP_MEMORY_SCOPE_AGENT);
}

// ---------------------------------------------------------------------------
// prep: 4 weight hi/lo splits + zero Hpk (both layers) + zero flags, fused
// into one flat-indexed dispatch (replaces 4x split_w + 2x zero_kernel).
// ---------------------------------------------------------------------------
__global__ __launch_bounds__(256) void prep(
    const float* __restrict__ Whh0, const float* __restrict__ Whh1,
    const float* __restrict__ Wih1, const float* __restrict__ Wih0,
    __bf16* __restrict__ Whh0h, __bf16* __restrict__ Whh0l,
    __bf16* __restrict__ Whh1h, __bf16* __restrict__ Whh1l,
    __bf16* __restrict__ Wih1h, __bf16* __restrict__ Wih1l,
    __bf16* __restrict__ Wih0h, __bf16* __restrict__ Wih0l,
    unsigned int* __restrict__ Hpk,   // 2*NCH*HDIM u32, zeroed
    int* __restrict__ flags)          // 512 ints, zeroed
{
  const int NB = N3 * HDIM;      // 3,145,728
  const int NS = N3 * 512;       // 1,572,864
  int i = blockIdx.x * 256 + threadIdx.x;
  const float* src; __bf16 *dh, *dl; int j;
  if (i < NB)            { src = Whh0; dh = Whh0h; dl = Whh0l; j = i; }
  else if (i < 2 * NB)   { src = Whh1; dh = Whh1h; dl = Whh1l; j = i - NB; }
  else if (i < 3 * NB)   { src = Wih1; dh = Wih1h; dl = Wih1l; j = i - 2 * NB; }
  else if (i < 3 * NB + NS) { src = Wih0; dh = Wih0h; dl = Wih0l; j = i - 3 * NB; }
  else if (i < 3 * NB + NS + 2 * NCH * HDIM) { Hpk[i - 3 * NB - NS] = 0u; return; }
  else if (i < 3 * NB + NS + 2 * NCH * HDIM + 512) {
    flags[i - 3 * NB - NS - 2 * NCH * HDIM] = 0; return;
  }
  else return;
  float x = src[j];
  __bf16 h = (__bf16)x;
  dh[j] = h;
  dl[j] = (__bf16)(x - (float)h);
}

// ---------------------------------------------------------------------------
// xproj_mfma (verified): out[r,n] = x@W[n,:]+bias[n]
// 128 rows x 128 cols per block. Output is RAW pre-LN pi (bias included);
// the input-LN happens inside recur_pers.
// ---------------------------------------------------------------------------
__global__ __launch_bounds__(256) void xproj_mfma(
    const float* __restrict__ A0, const float* __restrict__ A1,
    int chainsA0, int strideChain, int t0, int K, int lTc,
    const __bf16* __restrict__ Wh, const __bf16* __restrict__ Wl,
    const float* __restrict__ bias, float* __restrict__ out)
{
  __shared__ __bf16 Ah[4][128][8];
  __shared__ __bf16 Al[4][128][8];
  const int tid  = threadIdx.x;
  const int n0   = blockIdx.x * 128;
  const int row0 = blockIdx.y * 128;
  const int lane = tid & 63;
  const int wv   = tid >> 6;
  const int q    = lane >> 4;
  const int c15  = lane & 15;
  const int m_off = wv * 32;
  const int sr  = tid >> 1;
  const int sq0 = (tid & 1) * 2;
  const int sk  = (tid & 1) * 16;
  const int r     = row0 + sr;
  const int chain = r >> lTc;
  const int dt    = r & ((1 << lTc) - 1);
  const float* aptr = (chain < chainsA0)
      ? (A0 + ((size_t)chain * strideChain + t0 + dt) * K)
      : (A1 + ((size_t)(chain - chainsA0) * strideChain + t0 + dt) * K);

  f32x4 acc[2][8];
#pragma unroll
  for (int i = 0; i < 2; ++i)
#pragma unroll
    for (int j = 0; j < 8; ++j) acc[i][j] = (f32x4){0.f, 0.f, 0.f, 0.f};

  for (int k0 = 0; k0 < K; k0 += 32) {
    float f[16];
    *(float4*)(f + 0)  = *(const float4*)(aptr + k0 + sk + 0);
    *(float4*)(f + 4)  = *(const float4*)(aptr + k0 + sk + 4);
    *(float4*)(f + 8)  = *(const float4*)(aptr + k0 + sk + 8);
    *(float4*)(f + 12) = *(const float4*)(aptr + k0 + sk + 12);
    bf16x8 hv0, hv1, lv0, lv1;
#pragma unroll
    for (int e = 0; e < 8; ++e) {
      __bf16 h0 = (__bf16)f[e];
      hv0[e] = h0;  lv0[e] = (__bf16)(f[e] - (float)h0);
      __bf16 h1 = (__bf16)f[8 + e];
      hv1[e] = h1;  lv1[e] = (__bf16)(f[8 + e] - (float)h1);
    }
    __syncthreads();
    *(bf16x8*)&Ah[sq0][sr][0]     = hv0;
    *(bf16x8*)&Ah[sq0 + 1][sr][0] = hv1;
    *(bf16x8*)&Al[sq0][sr][0]     = lv0;
    *(bf16x8*)&Al[sq0 + 1][sr][0] = lv1;
    __syncthreads();

    bf16x8 a_h[2], a_l[2];
#pragma unroll
    for (int i = 0; i < 2; ++i) {
      a_h[i] = *(const bf16x8*)&Ah[q][m_off + i * 16 + c15][0];
      a_l[i] = *(const bf16x8*)&Al[q][m_off + i * 16 + c15][0];
    }
#pragma unroll
    for (int j = 0; j < 8; ++j) {
      const size_t woff = (size_t)(n0 + j * 16 + c15) * K + k0 + q * 8;
      bf16x8 b_h = *(const bf16x8*)(Wh + woff);
      bf16x8 b_l = *(const bf16x8*)(Wl + woff);
#pragma unroll
      for (int i = 0; i < 2; ++i) {
        acc[i][j] = mfma_bf16(a_h[i], b_h, acc[i][j]);
        acc[i][j] = mfma_bf16(a_h[i], b_l, acc[i][j]);
        acc[i][j] = mfma_bf16(a_l[i], b_h, acc[i][j]);
      }
    }
  }

#pragma unroll
  for (int j = 0; j < 8; ++j) {
    const int col = n0 + j * 16 + c15;
    const float bcol = bias[col];
#pragma unroll
    for (int i = 0; i < 2; ++i) {
#pragma unroll
      for (int rr = 0; rr < 4; ++rr) {
        const int m = m_off + i * 16 + q * 4 + rr;
        out[(size_t)(row0 + m) * N3 + col] = acc[i][j][rr] + bcol;
      }
    }
  }
}

// ---------------------------------------------------------------------------
// recur_pers: persistent recurrence with FUSED input-LN (round-2 verified
// structure). ONLY change vs round 2: k-reduce pad restored 16 -> 20.
// Pad-16 put the b128 k-reduce write on 8 banks (8-way conflict, 18.9M
// SQ_LDS_BANK_CONFLICT, +127us); pad-20 is the round-0/1-proven layout
// (6.3M conflicts). LDS total 68,352B (>64KB is fine: round-3 ran 117KB
// on this exact launch config).
// 256 blocks x 512 thr. Group gid = bid>>5 owns chains [gid*16,+16);
// block ct = bid&31 owns cols [ct*32,+32) of each gate. Per-step stats
// exchange carries 12 values/chain ([0..5]=ph, [6..11]=pi sums/sumsqs).
// Epoch flags: value = base + dt + 1; flags zeroed once in prep.
// ---------------------------------------------------------------------------
__global__ __launch_bounds__(512, 2) void recur_pers(
    const __bf16* __restrict__ Wh, const __bf16* __restrict__ Wl,
    const float* __restrict__ bhh,
    const float* __restrict__ ghw, const float* __restrict__ ghb,
    const float* __restrict__ giw, const float* __restrict__ gib,  // input-LN affine
    const float* __restrict__ pi,        // RAW pre-LN pi (bias included)
    unsigned int* __restrict__ Hpk,      // [NCH][HDIM] u32: lo16=hi-bf16, hi16=lo-bf16
    float* __restrict__ h_carry,         // [NCH][HDIM] fp32, chunk carry
    float* __restrict__ hseq,            // layer0: [ch][Tc][HDIM]; layer1: null
    float* __restrict__ stats_part,      // [8][32][192]  j = m*12 + idx
    int* __restrict__ flag_a, int* __restrict__ flag_b,   // [8*32]
    int Tc, int firstChunk, int base)
{
  const int tid  = threadIdx.x;
  const int bid  = blockIdx.x;
  const int gid  = bid >> 5;
  const int ct   = bid & 31;
  const int lane = tid & 63;
  const int w    = tid >> 6;        // wave 0..7 -> k-slice
  const int q    = lane >> 4;
  const int c15  = lane & 15;
  // phase-B mapping
  const int m    = tid & 15;        // chain within group
  const int col  = tid >> 4;        // 0..31 within col slice
  const int ch   = gid * 16 + m;
  const int Hcol = ct * 32 + col;

  __shared__ float red[8 * 6 * 16 * 20];   // phase A: [w][t][n16][m(20 pad)]; reused in gather
  __shared__ float sred[8 * 16 * 12];      // [w][m][12]
  __shared__ float sstat[192];             // [m][12]

  // ---- preload weight fragments into registers (hi/lo) ----
  bf16x8 bh[6][4], bl[6][4];
  const int kw = w * 128;
#pragma unroll
  for (int t = 0; t < 6; ++t) {
    const int gate = t >> 1, half = t & 1;
    const size_t nrow = (size_t)(gate * 1024 + ct * 32 + half * 16 + c15);
#pragma unroll
    for (int kc = 0; kc < 4; ++kc) {
      const size_t off = nrow * HDIM + kw + kc * 32 + q * 8;
      bh[t][kc] = *(const bf16x8*)(Wh + off);
      bl[t][kc] = *(const bf16x8*)(Wl + off);
    }
  }

  // per-thread constants (phase B)
  const float bias0 = bhh[Hcol], bias1 = bhh[1024 + Hcol], bias2 = bhh[2048 + Hcol];
  const float lw0 = ghw[Hcol], lw1 = ghw[1024 + Hcol], lw2 = ghw[2048 + Hcol];
  const float lb0 = ghb[Hcol], lb1 = ghb[1024 + Hcol], lb2 = ghb[2048 + Hcol];
  const float iw0 = giw[Hcol], iw1 = giw[1024 + Hcol], iw2 = giw[2048 + Hcol];
  const float ib0 = gib[Hcol], ib1 = gib[1024 + Hcol], ib2 = gib[2048 + Hcol];
  float hprev = firstChunk ? 0.f : h_carry[(size_t)ch * HDIM + Hcol];

  const size_t arowbase = (size_t)(gid * 16 + c15) * HDIM;
  float* my_part = stats_part + ((size_t)gid * 32 + ct) * 192;
  const int* fA = flag_a + (gid << 5);
  const int* fB = flag_b + (gid << 5);
  const int pidx = lane & 31;

  for (int dt = 0; dt < Tc; ++dt) {
    // prefetch RAW pi for stats + phase B (overlaps the poll)
    const float* pirow = pi + ((size_t)ch * Tc + dt) * N3 + Hcol;
    const float pr = pirow[0], pz = pirow[1024], pn = pirow[2048];

    // ---- wait until h(dt-1) published by all 32 blocks of the group ----
    if (w == 0 && dt > 0) {
      while (true) {
        int v = ld_sc1_i32(fB + pidx);
        if (!__any(v < base + dt)) break;
        __builtin_amdgcn_s_sleep(1);
      }
    }
    __syncthreads();
    __asm__ __volatile__("" ::: "memory");

    // ---- phase A: GEMM slice (k-split across waves) ----
    f32x4 acc[6];
#pragma unroll
    for (int t = 0; t < 6; ++t) acc[t] = (f32x4){0.f, 0.f, 0.f, 0.f};

    unsigned long long abuf[2][4];
#pragma unroll
    for (int j = 0; j < 4; ++j) {
      abuf[0][j] = ld_sc1_u64((const unsigned long long*)(Hpk + arowbase + kw + 0 * 32 + q * 8) + j);
      abuf[1][j] = ld_sc1_u64((const unsigned long long*)(Hpk + arowbase + kw + 1 * 32 + q * 8) + j);
    }
#pragma unroll
    for (int kc = 0; kc < 4; ++kc) {
      unsigned int u[8];
#pragma unroll
      for (int j = 0; j < 4; ++j) {
        u[2 * j]     = (unsigned int)(abuf[kc & 1][j]);
        u[2 * j + 1] = (unsigned int)(abuf[kc & 1][j] >> 32);
      }
      union { unsigned int d[4]; bf16x8 v; } uah, ual;
#pragma unroll
      for (int d = 0; d < 4; ++d) {
        uah.d[d] = __builtin_amdgcn_perm(u[2 * d + 1], u[2 * d], 0x05040100u);
        ual.d[d] = __builtin_amdgcn_perm(u[2 * d + 1], u[2 * d], 0x07060302u);
      }
      if (kc < 2) {
#pragma unroll
        for (int j = 0; j < 4; ++j)
          abuf[kc & 1][j] = ld_sc1_u64(
              (const unsigned long long*)(Hpk + arowbase + kw + (kc + 2) * 32 + q * 8) + j);
      }
      bf16x8 ah = uah.v, al = ual.v;
#pragma unroll
      for (int t = 0; t < 6; ++t) {
        acc[t] = mfma_bf16(ah, bh[t][kc], acc[t]);
        acc[t] = mfma_bf16(ah, bl[t][kc], acc[t]);
        acc[t] = mfma_bf16(al, bh[t][kc], acc[t]);
      }
    }

    // ---- k-reduce via LDS (pad 20, bank-safe) ----
#pragma unroll
    for (int t = 0; t < 6; ++t) {
      const int idx = ((w * 6 + t) * 16 + c15) * 20 + q * 4;
      *(f32x4*)&red[idx] = acc[t];
    }
    __syncthreads();

    float phv0 = 0.f, phv1 = 0.f, phv2 = 0.f;
    {
      const int cn = col & 15;
      const int hi = col >> 4;
#pragma unroll
      for (int w8 = 0; w8 < 8; ++w8) {
        phv0 += red[((w8 * 6 + 0 * 2 + hi) * 16 + cn) * 20 + m];
        phv1 += red[((w8 * 6 + 1 * 2 + hi) * 16 + cn) * 20 + m];
        phv2 += red[((w8 * 6 + 2 * 2 + hi) * 16 + cn) * 20 + m];
      }
    }
    phv0 += bias0; phv1 += bias1; phv2 += bias2;

    // ---- per-wave LN partials (ph AND pi) -> sred ----
    {
      float s0 = phv0, s1 = phv1, s2 = phv2;
      float q0 = phv0 * phv0, q1 = phv1 * phv1, q2 = phv2 * phv2;
      float s3 = pr, s4 = pz, s5 = pn;
      float q3 = pr * pr, q4 = pz * pz, q5 = pn * pn;
#pragma unroll
      for (int mm = 16; mm <= 32; mm <<= 1) {
        s0 += __shfl_xor(s0, mm); q0 += __shfl_xor(q0, mm);
        s1 += __shfl_xor(s1, mm); q1 += __shfl_xor(q1, mm);
        s2 += __shfl_xor(s2, mm); q2 += __shfl_xor(q2, mm);
        s3 += __shfl_xor(s3, mm); q3 += __shfl_xor(q3, mm);
        s4 += __shfl_xor(s4, mm); q4 += __shfl_xor(q4, mm);
        s5 += __shfl_xor(s5, mm); q5 += __shfl_xor(q5, mm);
      }
      if (lane < 16) {
        const int b = (w * 16 + lane) * 12;
        sred[b + 0] = s0;  sred[b + 1] = q0;
        sred[b + 2] = s1;  sred[b + 3] = q1;
        sred[b + 4] = s2;  sred[b + 5] = q2;
        sred[b + 6] = s3;  sred[b + 7] = q3;
        sred[b + 8] = s4;  sred[b + 9] = q4;
        sred[b + 10] = s5; sred[b + 11] = q5;
      }
    }
    __syncthreads();

    // ---- block partials -> IC (j = m*12 + idx, contiguous per chain) ----
    if (tid < 192) {
      const int m12 = tid / 12;
      const int r12 = tid - m12 * 12;
      float v = 0.f;
#pragma unroll
      for (int w8 = 0; w8 < 8; ++w8) v += sred[(w8 * 16 + m12) * 12 + r12];
      st_sc1_f32(&my_part[tid], v);
    }
    __syncthreads();   // drains vmcnt on all waves -> partials visible at IC
    if (tid == 0) st_sc1_i32((int*)fA + ct, base + dt + 1);

    // ---- wait all blocks' partials ----
    if (w == 0) {
      while (true) {
        int v = ld_sc1_i32(fA + pidx);
        if (!__any(v < base + dt + 1)) break;
        __builtin_amdgcn_s_sleep(1);
      }
    }
    __syncthreads();
    __asm__ __volatile__("" ::: "memory");

    // ---- gather stats: all 512 threads, 12 loads each; 2-stage reduce ----
    {
      const int cidx = tid >> 4;   // source block 0..31
      const float* sp = stats_part + ((size_t)gid * 32 + cidx) * 192 + m * 12;
      float p0 = ld_sc1_f32(sp + 0),  p1 = ld_sc1_f32(sp + 1),  p2 = ld_sc1_f32(sp + 2);
      float p3 = ld_sc1_f32(sp + 3),  p4 = ld_sc1_f32(sp + 4),  p5 = ld_sc1_f32(sp + 5);
      float p6 = ld_sc1_f32(sp + 6),  p7 = ld_sc1_f32(sp + 7),  p8 = ld_sc1_f32(sp + 8);
      float p9 = ld_sc1_f32(sp + 9),  p10 = ld_sc1_f32(sp + 10), p11 = ld_sc1_f32(sp + 11);
      p0 += __shfl_xor(p0, 16); p1 += __shfl_xor(p1, 16); p2 += __shfl_xor(p2, 16);
      p3 += __shfl_xor(p3, 16); p4 += __shfl_xor(p4, 16); p5 += __shfl_xor(p5, 16);
      p6 += __shfl_xor(p6, 16); p7 += __shfl_xor(p7, 16); p8 += __shfl_xor(p8, 16);
      p9 += __shfl_xor(p9, 16); p10 += __shfl_xor(p10, 16); p11 += __shfl_xor(p11, 16);
      p0 += __shfl_xor(p0, 32); p1 += __shfl_xor(p1, 32); p2 += __shfl_xor(p2, 32);
      p3 += __shfl_xor(p3, 32); p4 += __shfl_xor(p4, 32); p5 += __shfl_xor(p5, 32);
      p6 += __shfl_xor(p6, 32); p7 += __shfl_xor(p7, 32); p8 += __shfl_xor(p8, 32);
      p9 += __shfl_xor(p9, 32); p10 += __shfl_xor(p10, 32); p11 += __shfl_xor(p11, 32);
      if (lane < 16) {           // per-wave partial over its 4 source blocks
        const int b = w * 200 + lane * 12;    // reuse `red`, stride 200
        red[b + 0] = p0;  red[b + 1] = p1;  red[b + 2] = p2;
        red[b + 3] = p3;  red[b + 4] = p4;  red[b + 5] = p5;
        red[b + 6] = p6;  red[b + 7] = p7;  red[b + 8] = p8;
        red[b + 9] = p9;  red[b + 10] = p10; red[b + 11] = p11;
      }
    }
    __syncthreads();
    if (tid < 192) {
      float v = 0.f;
#pragma unroll
      for (int w8 = 0; w8 < 8; ++w8) v += red[w8 * 200 + tid];
      sstat[tid] = v;
    }
    __syncthreads();

    // ---- phase B: both LNs + gate math + publish h(dt) ----
    {
      const int b = m * 12;
      const float mh0 = sstat[b + 0] * (1.f / 1024.f);
      const float vh0 = sstat[b + 1] * (1.f / 1024.f) - mh0 * mh0;
      const float mh1 = sstat[b + 2] * (1.f / 1024.f);
      const float vh1 = sstat[b + 3] * (1.f / 1024.f) - mh1 * mh1;
      const float mh2 = sstat[b + 4] * (1.f / 1024.f);
      const float vh2 = sstat[b + 5] * (1.f / 1024.f) - mh2 * mh2;
      const float mi0 = sstat[b + 6] * (1.f / 1024.f);
      const float vi0 = sstat[b + 7] * (1.f / 1024.f) - mi0 * mi0;
      const float mi1 = sstat[b + 8] * (1.f / 1024.f);
      const float vi1 = sstat[b + 9] * (1.f / 1024.f) - mi1 * mi1;
      const float mi2 = sstat[b + 10] * (1.f / 1024.f);
      const float vi2 = sstat[b + 11] * (1.f / 1024.f) - mi2 * mi2;
      const float nh0 = (phv0 - mh0) * rsqrtf(vh0 + 1e-5f) * lw0 + lb0;
      const float nh1 = (phv1 - mh1) * rsqrtf(vh1 + 1e-5f) * lw1 + lb1;
      const float nh2 = (phv2 - mh2) * rsqrtf(vh2 + 1e-5f) * lw2 + lb2;
      const float ni0 = (pr - mi0) * rsqrtf(vi0 + 1e-5f) * iw0 + ib0;
      const float ni1 = (pz - mi1) * rsqrtf(vi1 + 1e-5f) * iw1 + ib1;
      const float ni2 = (pn - mi2) * rsqrtf(vi2 + 1e-5f) * iw2 + ib2;
      const float r  = 1.f / (1.f + expf(-(ni0 + nh0)));
      const float z  = 1.f / (1.f + expf(-(ni1 + nh1)));
      const float nn = tanhf(ni2 + r * nh2);
      const float hn = (1.f - z) * nn + z * hprev;
      hprev = hn;
      const __bf16 hb = (__bf16)hn;
      const __bf16 lo = (__bf16)(hn - (float)hb);
      unsigned short hs, ls;
      __builtin_memcpy(&hs, &hb, 2);
      __builtin_memcpy(&ls, &lo, 2);
      st_sc1_u32(Hpk + (size_t)ch * HDIM + Hcol,
                 (unsigned int)hs | ((unsigned int)ls << 16));
      if (hseq) hseq[((size_t)ch * Tc + dt) * HDIM + Hcol] = hn;
      if (dt == Tc - 1) h_carry[(size_t)ch * HDIM + Hcol] = hn;
    }
    __syncthreads();   // drains vmcnt -> h visible at IC
    if (tid == 0) st_sc1_i32((int*)fB + ct, base + dt + 1);
  }
}

// ---------------------------------------------------------------------------
// readout: label (128 x dot-1024) + loss reduce, fused into one dispatch.
// 1 block x 1024 threads; wave w handles chains [w*8, w*8+8).
// ---------------------------------------------------------------------------
__global__ __launch_bounds__(1024) void readout(const float* __restrict__ h,
    const float* __restrict__ Wout, const float* __restrict__ bout,
    float* __restrict__ out)
{
  const int tid  = threadIdx.x;
  const int lane = tid & 63;
  const int w    = tid >> 6;
  __shared__ float lab[128];
  __shared__ float rg[2], rt[2];
  const int c  = w * 8 + (lane >> 3);
  const int j0 = (lane & 7) * 128;
  const float* hp = h + (size_t)c * HDIM + j0;
  float s = 0.f;
#pragma unroll
  for (int j = 0; j < 128; j += 4) {
    float4 v  = *(const float4*)(hp + j);
    float4 wv = *(const float4*)(Wout + j0 + j);
    s += v.x * wv.x + v.y * wv.y + v.z * wv.z + v.w * wv.w;
  }
  s += __shfl_xor(s, 1);
  s += __shfl_xor(s, 2);
  s += __shfl_xor(s, 4);
  if ((lane & 7) == 0) lab[c] = s + bout[0];
  __syncthreads();
  if (tid < 128) {
    float v = lab[tid];
    float g = (tid < 64) ? v : 0.f;
    float t = (tid >= 64) ? v : 0.f;
#pragma unroll
    for (int off = 32; off > 0; off >>= 1) {
      g += __shfl_down(g, off);
      t += __shfl_down(t, off);
    }
    if ((tid & 63) == 0) { rg[tid >> 6] = g; rt[tid >> 6] = t; }
  }
  __syncthreads();
  if (tid == 0) {
    float gm = (rg[0] + rg[1]) * (1.f / 64.f);
    float tm = (rt[0] + rt[1]) * (1.f / 64.f);
    out[0] = -tm + gm;
    out[1] = -gm;
  }
}

// ---------------------------------------------------------------------------
extern "C" void kernel_launch(void* const* d_in, const int* in_sizes, int n_in,
                              void* d_out, int out_size, void* d_ws, size_t ws_size,
                              hipStream_t stream)
{
  const float* gen  = (const float*)d_in[0];
  const float* tru  = (const float*)d_in[1];
  const float* Wih0 = (const float*)d_in[2];
  const float* Whh0 = (const float*)d_in[3];
  const float* bih0 = (const float*)d_in[4];
  const float* bhh0 = (const float*)d_in[5];
  const float* gig0 = (const float*)d_in[6];
  const float* gib0 = (const float*)d_in[7];
  const float* ghg0 = (const float*)d_in[8];
  const float* ghb0 = (const float*)d_in[9];
  const float* Wih1 = (const float*)d_in[10];
  const float* Whh1 = (const float*)d_in[11];
  const float* bih1 = (const float*)d_in[12];
  const float* bhh1 = (const float*)d_in[13];
  const float* gig1 = (const float*)d_in[14];
  const float* gib1 = (const float*)d_in[15];
  const float* ghg1 = (const float*)d_in[16];
  const float* ghb1 = (const float*)d_in[17];
  const float* Wout = (const float*)d_in[18];
  const float* bout = (const float*)d_in[19];
  float* out = (float*)d_out;

  // ---- bf16 hi/lo weights ----
  __bf16* bp = (__bf16*)d_ws;
  __bf16* Whh0h = bp;  bp += (size_t)N3 * HDIM;
  __bf16* Whh0l = bp;  bp += (size_t)N3 * HDIM;
  __bf16* Whh1h = bp;  bp += (size_t)N3 * HDIM;
  __bf16* Whh1l = bp;  bp += (size_t)N3 * HDIM;
  __bf16* Wih1h = bp;  bp += (size_t)N3 * HDIM;
  __bf16* Wih1l = bp;  bp += (size_t)N3 * HDIM;
  __bf16* Wih0h = bp;  bp += (size_t)N3 * 512;
  __bf16* Wih0l = bp;  bp += (size_t)N3 * 512;
  unsigned int* H0pk = (unsigned int*)bp;
  unsigned int* H1pk = H0pk + (size_t)NCH * HDIM;
  const size_t bf16Bytes = ((char*)(H1pk + (size_t)NCH * HDIM)) - (char*)d_ws;

  // ---- float region ----
  const size_t fixedF = 2 * (size_t)NCH * HDIM + 8 * 32 * 192 + 1024;
  int Tc = 256;
  while (Tc > 1) {
    size_t needF = (size_t)NCH * Tc * (N3 + HDIM) + fixedF;
    if (bf16Bytes + needF * 4 <= ws_size) break;
    Tc >>= 1;
  }
  int lTc = 0;
  while ((1 << lTc) < Tc) ++lTc;

  float* fp       = (float*)((char*)d_ws + bf16Bytes);
  float* pi_chunk = fp;   fp += (size_t)NCH * Tc * N3;
  float* h0_chunk = fp;   fp += (size_t)NCH * Tc * HDIM;
  float* h_cur0   = fp;   fp += (size_t)NCH * HDIM;
  float* h_cur1   = fp;   fp += (size_t)NCH * HDIM;
  float* stats    = fp;   fp += 8 * 32 * 192;
  int*   flag_a   = (int*)fp;          // 256 ints
  int*   flag_b   = flag_a + 256;      // 256 ints (+ pad within 1024 floats)

  // ---- prep: weight splits + Hpk zero + flag zero (one dispatch) ----
  {
    const int total = 3 * (N3 * HDIM) + (N3 * 512) + 2 * NCH * HDIM + 512;
    prep<<<(total + 255) / 256, 256, 0, stream>>>(
        Whh0, Whh1, Wih1, Wih0,
        Whh0h, Whh0l, Whh1h, Whh1l, Wih1h, Wih1l, Wih0h, Wih0l,
        H0pk, flag_a);
  }

  const int nChunks = SLEN / Tc;
  for (int cidx = 0; cidx < nChunks; ++cidx) {
    const int t0 = cidx * Tc;
    const int first = (cidx == 0) ? 1 : 0;
    // ---- layer 0: xproj (raw pi) -> recurrence with fused LN ----
    xproj_mfma<<<dim3(24, Tc), 256, 0, stream>>>(
        gen, tru, 64, SLEN, t0, 512, lTc, Wih0h, Wih0l, bih0, pi_chunk);
    recur_pers<<<256, 512, 0, stream>>>(
        Whh0h, Whh0l, bhh0, ghg0, ghb0, gig0, gib0, pi_chunk, H0pk, h_cur0,
        h0_chunk, stats, flag_a, flag_b, Tc, first, (cidx * 2 + 0) * Tc);
    // ---- layer 1 ----
    xproj_mfma<<<dim3(24, Tc), 256, 0, stream>>>(
        h0_chunk, h0_chunk, NCH, Tc, 0, 1024, lTc, Wih1h, Wih1l, bih1, pi_chunk);
    recur_pers<<<256, 512, 0, stream>>>(
        Whh1h, Whh1l, bhh1, ghg1, ghb1, gig1, gib1, pi_chunk, H1pk, h_cur1,
        (float*)nullptr, stats, flag_a, flag_b, Tc, first, (cidx * 2 + 1) * Tc);
  }

  // ---- readout (label + loss fused) ----
  readout<<<1, 1024, 0, stream>>>(h_cur1, Wout, bout, out);
}

// Round 7
// 9417.519 us; speedup vs baseline: 1.4565x; 1.2004x over previous
//
#include <hip/hip_runtime.h>
#include <math.h>

#define NCH   128          // chains = 2*B (0..63 = generated, 64..127 = true)
#define SLEN  256
#define HDIM  1024
#define N3    3072

typedef __attribute__((ext_vector_type(8))) __bf16 bf16x8;
typedef __attribute__((ext_vector_type(4))) float  f32x4;

__device__ __forceinline__ f32x4 mfma_bf16(bf16x8 a, bf16x8 b, f32x4 c) {
  return __builtin_amdgcn_mfma_f32_16x16x32_bf16(a, b, c, 0, 0, 0);
}

// ---- agent-scope (sc1 / IC-coherent) accessors
__device__ __forceinline__ float ld_sc1_f32(const float* p) {
  return __hip_atomic_load(p, __ATOMIC_RELAXED, __HIP_MEMORY_SCOPE_AGENT);
}
__device__ __forceinline__ void st_sc1_f32(float* p, float v) {
  __hip_atomic_store(p, v, __ATOMIC_RELAXED, __HIP_MEMORY_SCOPE_AGENT);
}
__device__ __forceinline__ unsigned long long ld_sc1_u64(const unsigned long long* p) {
  return __hip_atomic_load(p, __ATOMIC_RELAXED, __HIP_MEMORY_SCOPE_AGENT);
}
__device__ __forceinline__ void st_sc1_u32(unsigned int* p, unsigned int v) {
  __hip_atomic_store(p, v, __ATOMIC_RELAXED, __HIP_MEMORY_SCOPE_AGENT);
}
__device__ __forceinline__ int ld_sc1_i32(const int* p) {
  return __hip_atomic_load(p, __ATOMIC_RELAXED, __HIP_MEMORY_SCOPE_AGENT);
}
__device__ __forceinline__ void st_sc1_i32(int* p, int v) {
  __hip_atomic_store(p, v, __ATOMIC_RELAXED, __HIP_MEMORY_SCOPE_AGENT);
}

// ---------------------------------------------------------------------------
__global__ void split_w(const float* __restrict__ src, __bf16* __restrict__ dh,
                        __bf16* __restrict__ dl, int n)
{
  int i = blockIdx.x * blockDim.x + threadIdx.x;
  if (i < n) {
    float x = src[i];
    __bf16 h = (__bf16)x;
    float r = x - (float)h;
    dh[i] = h;
    dl[i] = (__bf16)r;
  }
}

__global__ void zero_kernel(float* __restrict__ p, int n)
{
  int i = blockIdx.x * blockDim.x + threadIdx.x;
  if (i < n) p[i] = 0.f;
}

// ---------------------------------------------------------------------------
// xproj_mfma: out[r,n] = x_row(r)@W[n,:]+bias[n]
// 128 rows x 128 cols per block (grid.x = N3/128 = 24) — halves the redundant
// A-tile re-read vs the previous 64-col tiling (A traffic scales with grid.x).
// Same K-loop order per output element => bit-identical results.
// ---------------------------------------------------------------------------
__global__ __launch_bounds__(256) void xproj_mfma(
    const float* __restrict__ A0, const float* __restrict__ A1,
    int chainsA0, int strideChain, int t0, int K, int lTc,
    const __bf16* __restrict__ Wh, const __bf16* __restrict__ Wl,
    const float* __restrict__ bias, float* __restrict__ out)
{
  __shared__ __bf16 Ah[4][128][8];
  __shared__ __bf16 Al[4][128][8];
  const int tid  = threadIdx.x;
  const int n0   = blockIdx.x * 128;
  const int row0 = blockIdx.y * 128;
  const int lane = tid & 63;
  const int wv   = tid >> 6;
  const int q    = lane >> 4;
  const int c15  = lane & 15;
  const int m_off = wv * 32;
  const int sr  = tid >> 1;
  const int sq0 = (tid & 1) * 2;
  const int sk  = (tid & 1) * 16;
  const int r     = row0 + sr;
  const int chain = r >> lTc;
  const int dt    = r & ((1 << lTc) - 1);
  const float* aptr = (chain < chainsA0)
      ? (A0 + ((size_t)chain * strideChain + t0 + dt) * K)
      : (A1 + ((size_t)(chain - chainsA0) * strideChain + t0 + dt) * K);

  f32x4 acc[2][8];
#pragma unroll
  for (int i = 0; i < 2; ++i)
#pragma unroll
    for (int j = 0; j < 8; ++j) acc[i][j] = (f32x4){0.f, 0.f, 0.f, 0.f};

  for (int k0 = 0; k0 < K; k0 += 32) {
    float f[16];
    *(float4*)(f + 0)  = *(const float4*)(aptr + k0 + sk + 0);
    *(float4*)(f + 4)  = *(const float4*)(aptr + k0 + sk + 4);
    *(float4*)(f + 8)  = *(const float4*)(aptr + k0 + sk + 8);
    *(float4*)(f + 12) = *(const float4*)(aptr + k0 + sk + 12);
    bf16x8 hv0, hv1, lv0, lv1;
#pragma unroll
    for (int e = 0; e < 8; ++e) {
      __bf16 h0 = (__bf16)f[e];
      hv0[e] = h0;  lv0[e] = (__bf16)(f[e] - (float)h0);
      __bf16 h1 = (__bf16)f[8 + e];
      hv1[e] = h1;  lv1[e] = (__bf16)(f[8 + e] - (float)h1);
    }
    __syncthreads();
    *(bf16x8*)&Ah[sq0][sr][0]     = hv0;
    *(bf16x8*)&Ah[sq0 + 1][sr][0] = hv1;
    *(bf16x8*)&Al[sq0][sr][0]     = lv0;
    *(bf16x8*)&Al[sq0 + 1][sr][0] = lv1;
    __syncthreads();

    bf16x8 a_h[2], a_l[2];
#pragma unroll
    for (int i = 0; i < 2; ++i) {
      a_h[i] = *(const bf16x8*)&Ah[q][m_off + i * 16 + c15][0];
      a_l[i] = *(const bf16x8*)&Al[q][m_off + i * 16 + c15][0];
    }
#pragma unroll
    for (int j = 0; j < 8; ++j) {
      const size_t woff = (size_t)(n0 + j * 16 + c15) * K + k0 + q * 8;
      bf16x8 b_h = *(const bf16x8*)(Wh + woff);
      bf16x8 b_l = *(const bf16x8*)(Wl + woff);
#pragma unroll
      for (int i = 0; i < 2; ++i) {
        acc[i][j] = mfma_bf16(a_h[i], b_h, acc[i][j]);
        acc[i][j] = mfma_bf16(a_h[i], b_l, acc[i][j]);
        acc[i][j] = mfma_bf16(a_l[i], b_h, acc[i][j]);
      }
    }
  }

#pragma unroll
  for (int j = 0; j < 8; ++j) {
    const int col = n0 + j * 16 + c15;
    const float bcol = bias[col];
#pragma unroll
    for (int i = 0; i < 2; ++i) {
#pragma unroll
      for (int rr = 0; rr < 4; ++rr) {
        const int m = m_off + i * 16 + q * 4 + rr;
        out[(size_t)(row0 + m) * N3 + col] = acc[i][j][rr] + bcol;
      }
    }
  }
}

// ---------------------------------------------------------------------------
// ln_rows: one block per (row, gate) — gates in parallel instead of the
// previous serial 3-gate loop (6 barriers -> 2 per 1024-elem slice).
// ---------------------------------------------------------------------------
__global__ __launch_bounds__(256) void ln_rows(float* __restrict__ a,
    const float* __restrict__ gw, const float* __restrict__ gb)
{
  const int row = blockIdx.x;
  const int g   = blockIdx.y;
  const int tid = threadIdx.x;
  float* base = a + (size_t)row * N3 + g * 1024;
  __shared__ float redS[4], redS2[4];
  __shared__ float s_mean, s_rstd;
  const int j = tid * 4;
  float4 v = *(const float4*)(base + j);
  float s  = v.x + v.y + v.z + v.w;
  float s2 = v.x*v.x + v.y*v.y + v.z*v.z + v.w*v.w;
#pragma unroll
  for (int off = 32; off > 0; off >>= 1) {
    s  += __shfl_down(s, off);
    s2 += __shfl_down(s2, off);
  }
  if ((tid & 63) == 0) { redS[tid >> 6] = s; redS2[tid >> 6] = s2; }
  __syncthreads();
  if (tid == 0) {
    float S  = redS[0] + redS[1] + redS[2] + redS[3];
    float S2 = redS2[0] + redS2[1] + redS2[2] + redS2[3];
    float mean = S * (1.f / 1024.f);
    float var  = S2 * (1.f / 1024.f) - mean * mean;
    s_mean = mean;
    s_rstd = rsqrtf(var + 1e-5f);
  }
  __syncthreads();
  float mean = s_mean, rstd = s_rstd;
  float4 gwv = *(const float4*)(gw + g * 1024 + j);
  float4 gbv = *(const float4*)(gb + g * 1024 + j);
  float4 o;
  o.x = (v.x - mean) * rstd * gwv.x + gbv.x;
  o.y = (v.y - mean) * rstd * gwv.y + gbv.y;
  o.z = (v.z - mean) * rstd * gwv.z + gbv.z;
  o.w = (v.w - mean) * rstd * gwv.w + gbv.w;
  *(float4*)(base + j) = o;
}

// ---------------------------------------------------------------------------
// recur_pers: persistent recurrence, flag-based group sync (no atomic RMW).
// 256 blocks x 512 thr. Group gid = bid>>5 owns chains [gid*16,+16); block
// ct = bid&31 owns cols [ct*32,+32) of each gate; waves split K, weights in
// registers. Cross-block data via sc1 (IC). Per-block sequence flags:
//   flag_a[gid*32+ct] = dt+1  after LN-partials written (phase A done)
//   flag_b[gid*32+ct] = dt+1  after h(dt) written        (phase B done)
// __syncthreads() before each flag store drains vmcnt on all waves (ordering).
// NOTE: launched as a REGULAR kernel (not cooperative). Co-residency is
// guaranteed: __launch_bounds__(512,2) + 65KB LDS => 2 blocks/CU, 512
// resident slots on 256 CUs for 256 blocks, stream is idle at launch.
// The kernel never uses grid.sync(); all sync is flag-based at agent scope.
// ---------------------------------------------------------------------------
__global__ __launch_bounds__(512, 2) void recur_pers(
    const __bf16* __restrict__ Wh, const __bf16* __restrict__ Wl,
    const float* __restrict__ bhh,
    const float* __restrict__ ghw, const float* __restrict__ ghb,
    const float* __restrict__ pi,
    unsigned int* __restrict__ Hpk,      // [NCH][HDIM] u32: lo16=hi-bf16, hi16=lo-bf16
    float* __restrict__ h_carry,         // [NCH][HDIM] fp32, chunk carry
    float* __restrict__ hseq,            // layer0: [ch][Tc][HDIM]; layer1: null
    float* __restrict__ stats_part,      // [8][32][96]  j = m*6 + g*2 + {sum,sumsq}
    int* __restrict__ flag_a, int* __restrict__ flag_b,   // [8*32]
    int Tc, int firstChunk)
{
  const int tid  = threadIdx.x;
  const int bid  = blockIdx.x;
  const int gid  = bid >> 5;
  const int ct   = bid & 31;
  const int lane = tid & 63;
  const int w    = tid >> 6;        // wave 0..7 -> k-slice
  const int q    = lane >> 4;
  const int c15  = lane & 15;
  // phase-B mapping
  const int m    = tid & 15;        // chain within group
  const int col  = tid >> 4;        // 0..31 within col slice
  const int ch   = gid * 16 + m;
  const int Hcol = ct * 32 + col;

  __shared__ float red[8 * 6 * 16 * 20];   // phase A: [w][nt][n16][m(20 pad)]; reused in B
  __shared__ float sred[8 * 16 * 6];       // [w][m][g*2+st]
  __shared__ float sstat[96];

  // ---- preload weight fragments into registers (hi/lo) ----
  bf16x8 bh[6][4], bl[6][4];
  const int kw = w * 128;
#pragma unroll
  for (int t = 0; t < 6; ++t) {
    const int gate = t >> 1, half = t & 1;
    const size_t nrow = (size_t)(gate * 1024 + ct * 32 + half * 16 + c15);
#pragma unroll
    for (int kc = 0; kc < 4; ++kc) {
      const size_t off = nrow * HDIM + kw + kc * 32 + q * 8;
      bh[t][kc] = *(const bf16x8*)(Wh + off);
      bl[t][kc] = *(const bf16x8*)(Wl + off);
    }
  }

  // per-thread constants (phase B)
  const float bias0 = bhh[Hcol], bias1 = bhh[1024 + Hcol], bias2 = bhh[2048 + Hcol];
  const float lw0 = ghw[Hcol], lw1 = ghw[1024 + Hcol], lw2 = ghw[2048 + Hcol];
  const float lb0 = ghb[Hcol], lb1 = ghb[1024 + Hcol], lb2 = ghb[2048 + Hcol];
  float hprev = firstChunk ? 0.f : h_carry[(size_t)ch * HDIM + Hcol];

  const size_t arowbase = (size_t)(gid * 16 + c15) * HDIM;
  float* my_part = stats_part + ((size_t)gid * 32 + ct) * 96;
  const int* fA = flag_a + (gid << 5);
  const int* fB = flag_b + (gid << 5);
  const int pidx = lane & 31;

  for (int dt = 0; dt < Tc; ++dt) {
    // prefetch pi for phase B (overlaps the poll)
    const float* pirow = pi + ((size_t)ch * Tc + dt) * N3 + Hcol;
    const float pr = pirow[0], pz = pirow[1024], pn = pirow[2048];

    // ---- wait until h(dt-1) published by all 32 blocks of the group ----
    if (w == 0 && dt > 0) {
      while (true) {
        int v = ld_sc1_i32(fB + pidx);
        if (!__any(v < dt)) break;
        __builtin_amdgcn_s_sleep(1);
      }
    }
    __syncthreads();
    __asm__ __volatile__("" ::: "memory");

    // ---- phase A: GEMM slice (k-split across waves) ----
    f32x4 acc[6];
#pragma unroll
    for (int t = 0; t < 6; ++t) acc[t] = (f32x4){0.f, 0.f, 0.f, 0.f};

    unsigned long long abuf[2][4];
#pragma unroll
    for (int j = 0; j < 4; ++j) {
      abuf[0][j] = ld_sc1_u64((const unsigned long long*)(Hpk + arowbase + kw + 0 * 32 + q * 8) + j);
      abuf[1][j] = ld_sc1_u64((const unsigned long long*)(Hpk + arowbase + kw + 1 * 32 + q * 8) + j);
    }
#pragma unroll
    for (int kc = 0; kc < 4; ++kc) {
      unsigned int u[8];
#pragma unroll
      for (int j = 0; j < 4; ++j) {
        u[2 * j]     = (unsigned int)(abuf[kc & 1][j]);
        u[2 * j + 1] = (unsigned int)(abuf[kc & 1][j] >> 32);
      }
      union { unsigned int d[4]; bf16x8 v; } uah, ual;
#pragma unroll
      for (int d = 0; d < 4; ++d) {
        uah.d[d] = __builtin_amdgcn_perm(u[2 * d + 1], u[2 * d], 0x05040100u);
        ual.d[d] = __builtin_amdgcn_perm(u[2 * d + 1], u[2 * d], 0x07060302u);
      }
      if (kc < 2) {
#pragma unroll
        for (int j = 0; j < 4; ++j)
          abuf[kc & 1][j] = ld_sc1_u64(
              (const unsigned long long*)(Hpk + arowbase + kw + (kc + 2) * 32 + q * 8) + j);
      }
      bf16x8 ah = uah.v, al = ual.v;
#pragma unroll
      for (int t = 0; t < 6; ++t) {
        acc[t] = mfma_bf16(ah, bh[t][kc], acc[t]);
        acc[t] = mfma_bf16(ah, bl[t][kc], acc[t]);
        acc[t] = mfma_bf16(al, bh[t][kc], acc[t]);
      }
    }

    // ---- k-reduce via LDS ----
#pragma unroll
    for (int t = 0; t < 6; ++t) {
      const int idx = ((w * 6 + t) * 16 + c15) * 20 + q * 4;
      *(f32x4*)&red[idx] = acc[t];
    }
    __syncthreads();

    float phv0 = 0.f, phv1 = 0.f, phv2 = 0.f;
    {
      const int cn = col & 15;
      const int hi = col >> 4;
#pragma unroll
      for (int w8 = 0; w8 < 8; ++w8) {
        phv0 += red[((w8 * 6 + 0 * 2 + hi) * 16 + cn) * 20 + m];
        phv1 += red[((w8 * 6 + 1 * 2 + hi) * 16 + cn) * 20 + m];
        phv2 += red[((w8 * 6 + 2 * 2 + hi) * 16 + cn) * 20 + m];
      }
    }
    phv0 += bias0; phv1 += bias1; phv2 += bias2;

    // ---- per-wave LN partials -> sred ----
    {
      float s0 = phv0, s1 = phv1, s2 = phv2;
      float q0 = phv0 * phv0, q1 = phv1 * phv1, q2 = phv2 * phv2;
#pragma unroll
      for (int mm = 16; mm <= 32; mm <<= 1) {
        s0 += __shfl_xor(s0, mm); q0 += __shfl_xor(q0, mm);
        s1 += __shfl_xor(s1, mm); q1 += __shfl_xor(q1, mm);
        s2 += __shfl_xor(s2, mm); q2 += __shfl_xor(q2, mm);
      }
      if (lane < 16) {
        const int b = (w * 16 + lane) * 6;
        sred[b + 0] = s0; sred[b + 1] = q0;
        sred[b + 2] = s1; sred[b + 3] = q1;
        sred[b + 4] = s2; sred[b + 5] = q2;
      }
    }
    __syncthreads();

    // ---- block partials -> IC (j = m*6 + g*2 + st, contiguous per chain) ----
    if (tid < 96) {
      const int m6 = tid / 6;
      const int r6 = tid - m6 * 6;
      float v = 0.f;
#pragma unroll
      for (int w8 = 0; w8 < 8; ++w8) v += sred[(w8 * 16 + m6) * 6 + r6];
      st_sc1_f32(&my_part[tid], v);
    }
    __syncthreads();   // drains vmcnt on all waves -> partials visible at IC
    if (tid == 0) st_sc1_i32((int*)fA + ct, dt + 1);

    // ---- wait all blocks' partials ----
    if (w == 0) {
      while (true) {
        int v = ld_sc1_i32(fA + pidx);
        if (!__any(v < dt + 1)) break;
        __builtin_amdgcn_s_sleep(1);
      }
    }
    __syncthreads();
    __asm__ __volatile__("" ::: "memory");

    // ---- gather stats: all 512 threads, 6 loads each; 2-stage reduce ----
    {
      const int cidx = tid >> 4;   // source block 0..31
      const float* sp = stats_part + ((size_t)gid * 32 + cidx) * 96 + m * 6;
      float p0 = ld_sc1_f32(sp + 0), p1 = ld_sc1_f32(sp + 1), p2 = ld_sc1_f32(sp + 2);
      float p3 = ld_sc1_f32(sp + 3), p4 = ld_sc1_f32(sp + 4), p5 = ld_sc1_f32(sp + 5);
      p0 += __shfl_xor(p0, 16); p1 += __shfl_xor(p1, 16); p2 += __shfl_xor(p2, 16);
      p3 += __shfl_xor(p3, 16); p4 += __shfl_xor(p4, 16); p5 += __shfl_xor(p5, 16);
      p0 += __shfl_xor(p0, 32); p1 += __shfl_xor(p1, 32); p2 += __shfl_xor(p2, 32);
      p3 += __shfl_xor(p3, 32); p4 += __shfl_xor(p4, 32); p5 += __shfl_xor(p5, 32);
      if (lane < 16) {           // per-wave partial over its 4 source blocks
        const int b = w * 104 + lane * 6;    // reuse `red`, stride 104 (bank-safe)
        red[b + 0] = p0; red[b + 1] = p1; red[b + 2] = p2;
        red[b + 3] = p3; red[b + 4] = p4; red[b + 5] = p5;
      }
    }
    __syncthreads();
    if (tid < 96) {
      float v = 0.f;
#pragma unroll
      for (int w8 = 0; w8 < 8; ++w8) v += red[w8 * 104 + tid];
      sstat[tid] = v;
    }
    __syncthreads();

    // ---- phase B: normalize + gate math + publish h(dt) ----
    {
      const int b = m * 6;
      const float mean0 = sstat[b + 0] * (1.f / 1024.f);
      const float var0  = sstat[b + 1] * (1.f / 1024.f) - mean0 * mean0;
      const float mean1 = sstat[b + 2] * (1.f / 1024.f);
      const float var1  = sstat[b + 3] * (1.f / 1024.f) - mean1 * mean1;
      const float mean2 = sstat[b + 4] * (1.f / 1024.f);
      const float var2  = sstat[b + 5] * (1.f / 1024.f) - mean2 * mean2;
      const float nh0 = (phv0 - mean0) * rsqrtf(var0 + 1e-5f) * lw0 + lb0;
      const float nh1 = (phv1 - mean1) * rsqrtf(var1 + 1e-5f) * lw1 + lb1;
      const float nh2 = (phv2 - mean2) * rsqrtf(var2 + 1e-5f) * lw2 + lb2;
      const float r  = 1.f / (1.f + expf(-(pr + nh0)));
      const float z  = 1.f / (1.f + expf(-(pz + nh1)));
      const float nn = tanhf(pn + r * nh2);
      const float hn = (1.f - z) * nn + z * hprev;
      hprev = hn;
      const __bf16 hb = (__bf16)hn;
      const __bf16 lo = (__bf16)(hn - (float)hb);
      unsigned short hs, ls;
      __builtin_memcpy(&hs, &hb, 2);
      __builtin_memcpy(&ls, &lo, 2);
      st_sc1_u32(Hpk + (size_t)ch * HDIM + Hcol,
                 (unsigned int)hs | ((unsigned int)ls << 16));
      if (hseq) hseq[((size_t)ch * Tc + dt) * HDIM + Hcol] = hn;
      if (dt == Tc - 1) h_carry[(size_t)ch * HDIM + Hcol] = hn;
    }
    __syncthreads();   // drains vmcnt -> h visible at IC
    if (tid == 0) st_sc1_i32((int*)fB + ct, dt + 1);
  }
}

// ---------------------------------------------------------------------------
__global__ __launch_bounds__(256) void label_kernel(const float* __restrict__ h,
    const float* __restrict__ Wout, const float* __restrict__ bout,
    float* __restrict__ labels)
{
  const int c = blockIdx.x;
  const int tid = threadIdx.x;
  __shared__ float red[4];
  float4 hv = *(const float4*)(h + (size_t)c * HDIM + tid * 4);
  float4 wv = *(const float4*)(Wout + tid * 4);
  float s = hv.x * wv.x + hv.y * wv.y + hv.z * wv.z + hv.w * wv.w;
#pragma unroll
  for (int off = 32; off > 0; off >>= 1) s += __shfl_down(s, off);
  if ((tid & 63) == 0) red[tid >> 6] = s;
  __syncthreads();
  if (tid == 0) labels[c] = red[0] + red[1] + red[2] + red[3] + bout[0];
}

__global__ void loss_kernel(const float* __restrict__ labels, float* __restrict__ out)
{
  const int tid = threadIdx.x;    // 128 threads
  __shared__ float rg[2], rt[2];
  float v = labels[tid];
  float g = (tid < 64) ? v : 0.f;
  float t = (tid >= 64) ? v : 0.f;
#pragma unroll
  for (int off = 32; off > 0; off >>= 1) {
    g += __shfl_down(g, off);
    t += __shfl_down(t, off);
  }
  if ((tid & 63) == 0) { rg[tid >> 6] = g; rt[tid >> 6] = t; }
  __syncthreads();
  if (tid == 0) {
    float gm = (rg[0] + rg[1]) * (1.f / 64.f);
    float tm = (rt[0] + rt[1]) * (1.f / 64.f);
    out[0] = -tm + gm;
    out[1] = -gm;
  }
}

// ---------------------------------------------------------------------------
extern "C" void kernel_launch(void* const* d_in, const int* in_sizes, int n_in,
                              void* d_out, int out_size, void* d_ws, size_t ws_size,
                              hipStream_t stream)
{
  const float* gen  = (const float*)d_in[0];
  const float* tru  = (const float*)d_in[1];
  const float* Wih0 = (const float*)d_in[2];
  const float* Whh0 = (const float*)d_in[3];
  const float* bih0 = (const float*)d_in[4];
  const float* bhh0 = (const float*)d_in[5];
  const float* gig0 = (const float*)d_in[6];
  const float* gib0 = (const float*)d_in[7];
  const float* ghg0 = (const float*)d_in[8];
  const float* ghb0 = (const float*)d_in[9];
  const float* Wih1 = (const float*)d_in[10];
  const float* Whh1 = (const float*)d_in[11];
  const float* bih1 = (const float*)d_in[12];
  const float* bhh1 = (const float*)d_in[13];
  const float* gig1 = (const float*)d_in[14];
  const float* gib1 = (const float*)d_in[15];
  const float* ghg1 = (const float*)d_in[16];
  const float* ghb1 = (const float*)d_in[17];
  const float* Wout = (const float*)d_in[18];
  const float* bout = (const float*)d_in[19];
  float* out = (float*)d_out;

  // ---- bf16 hi/lo weights ----
  __bf16* bp = (__bf16*)d_ws;
  __bf16* Whh0h = bp;  bp += (size_t)N3 * HDIM;
  __bf16* Whh0l = bp;  bp += (size_t)N3 * HDIM;
  __bf16* Whh1h = bp;  bp += (size_t)N3 * HDIM;
  __bf16* Whh1l = bp;  bp += (size_t)N3 * HDIM;
  __bf16* Wih1h = bp;  bp += (size_t)N3 * HDIM;
  __bf16* Wih1l = bp;  bp += (size_t)N3 * HDIM;
  __bf16* Wih0h = bp;  bp += (size_t)N3 * 512;
  __bf16* Wih0l = bp;  bp += (size_t)N3 * 512;
  unsigned int* H0pk = (unsigned int*)bp;
  unsigned int* H1pk = H0pk + (size_t)NCH * HDIM;
  const size_t bf16Bytes = ((char*)(H1pk + (size_t)NCH * HDIM)) - (char*)d_ws;

  // ---- float region ----
  const size_t fixedF = 2 * (size_t)NCH * HDIM + 256 + 8 * 32 * 96 + 1024;
  int Tc = 256;
  while (Tc > 1) {
    size_t needF = (size_t)NCH * Tc * (N3 + HDIM) + fixedF;
    if (bf16Bytes + needF * 4 <= ws_size) break;
    Tc >>= 1;
  }
  int lTc = 0;
  while ((1 << lTc) < Tc) ++lTc;

  float* fp       = (float*)((char*)d_ws + bf16Bytes);
  float* pi_chunk = fp;   fp += (size_t)NCH * Tc * N3;
  float* h0_chunk = fp;   fp += (size_t)NCH * Tc * HDIM;
  float* h_cur0   = fp;   fp += (size_t)NCH * HDIM;
  float* h_cur1   = fp;   fp += (size_t)NCH * HDIM;
  float* labels   = fp;   fp += 256;
  float* stats    = fp;   fp += 8 * 32 * 96;
  int*   flag_a   = (int*)fp;          // 256 ints
  int*   flag_b   = flag_a + 256;      // 256 ints (+ pad within 1024 floats)

  // ---- weight split (once per launch) ----
  {
    const int nW = N3 * HDIM;
    split_w<<<(nW + 255) / 256, 256, 0, stream>>>(Whh0, Whh0h, Whh0l, nW);
    split_w<<<(nW + 255) / 256, 256, 0, stream>>>(Whh1, Whh1h, Whh1l, nW);
    split_w<<<(nW + 255) / 256, 256, 0, stream>>>(Wih1, Wih1h, Wih1l, nW);
    const int nW0 = N3 * 512;
    split_w<<<(nW0 + 255) / 256, 256, 0, stream>>>(Wih0, Wih0h, Wih0l, nW0);
  }
  zero_kernel<<<(2 * NCH * HDIM) / 256, 256, 0, stream>>>((float*)H0pk, 2 * NCH * HDIM);

  const int nChunks = SLEN / Tc;
  for (int cidx = 0; cidx < nChunks; ++cidx) {
    const int t0 = cidx * Tc;
    const int first = (cidx == 0) ? 1 : 0;
    // ---- layer 0: xproj + LN ----
    xproj_mfma<<<dim3(24, Tc), 256, 0, stream>>>(
        gen, tru, 64, SLEN, t0, 512, lTc, Wih0h, Wih0l, bih0, pi_chunk);
    ln_rows<<<dim3(NCH * Tc, 3), 256, 0, stream>>>(pi_chunk, gig0, gib0);
    // ---- layer 0 recurrence (regular launch; co-residency by occupancy) ----
    zero_kernel<<<2, 256, 0, stream>>>((float*)flag_a, 512);
    recur_pers<<<256, 512, 0, stream>>>(
        Whh0h, Whh0l, bhh0, ghg0, ghb0, pi_chunk, H0pk, h_cur0,
        h0_chunk, stats, flag_a, flag_b, Tc, first);
    // ---- layer 1: xproj + LN from h0_chunk ----
    xproj_mfma<<<dim3(24, Tc), 256, 0, stream>>>(
        h0_chunk, h0_chunk, NCH, Tc, 0, 1024, lTc, Wih1h, Wih1l, bih1, pi_chunk);
    ln_rows<<<dim3(NCH * Tc, 3), 256, 0, stream>>>(pi_chunk, gig1, gib1);
    // ---- layer 1 recurrence ----
    zero_kernel<<<2, 256, 0, stream>>>((float*)flag_a, 512);
    recur_pers<<<256, 512, 0, stream>>>(
        Whh1h, Whh1l, bhh1, ghg1, ghb1, pi_chunk, H1pk, h_cur1,
        (float*)nullptr, stats, flag_a, flag_b, Tc, first);
  }

  // ---- readout ----
  label_kernel<<<NCH, 256, 0, stream>>>(h_cur1, Wout, bout, labels);
  loss_kernel<<<1, 128, 0, stream>>>(labels, out);
}